// Round 2
// baseline (324.325 us; speedup 1.0000x reference)
//
#include <hip/hip_runtime.h>

#define B_CONST 4096
#define S_CONST 4096
// T == 2 hardcoded throughout.

#define NEGBIG (-1e30f)

__device__ __forceinline__ float lse2(float a, float b) {
    float m = fmaxf(a, b);
    float d = fminf(a, b) - m;          // <= 0, finite (sentinels are -1e30, not -inf)
    return m + __logf(1.0f + __expf(d));
}

struct Seg { float m00, m01, m10, m11; };

__device__ __forceinline__ Seg seg_compose(const Seg& L, const Seg& R) {
    Seg o;
    o.m00 = lse2(L.m00 + R.m00, L.m01 + R.m10);
    o.m01 = lse2(L.m00 + R.m01, L.m01 + R.m11);
    o.m10 = lse2(L.m10 + R.m00, L.m11 + R.m10);
    o.m11 = lse2(L.m10 + R.m01, L.m11 + R.m11);
    return o;
}

// Kernel 0: one wave per row; 2-phase 64-ary search for L = count of leading 1s.
// mask row is a prefix of ones (arange < length), so ballot+popcount nails it
// in 2 dependent memory round trips (vs 12 for binary search).
__global__ __launch_bounds__(256) void crf_lens_kernel(
    const int* __restrict__ mask, int* __restrict__ lens)
{
    const int lane = threadIdx.x & 63;
    const int wid  = threadIdx.x >> 6;
    const int b    = blockIdx.x * 4 + wid;
    if (b >= B_CONST) return;
    const int* mk = mask + (size_t)b * S_CONST;

    // phase 1: v_i = (64*i < L)
    int v1 = mk[lane * 64];
    unsigned long long bal1 = __ballot(v1);
    int nb = __popcll(bal1);            // L in (64*(nb-1), 64*nb]
    int base = (nb - 1) * 64;
    // phase 2: exact within the bucket
    int v2 = mk[base + lane];
    unsigned long long bal2 = __ballot(v2);
    int L = base + __popcll(bal2);
    if (lane == 0) lens[b] = L;         // >= 1 always (lengths >= S/2)
}

// Kernel 1: one 1024-thread block per batch row; 4 steps/thread so wave loads
// are contiguous (2 KB emissions, 1 KB tags per wave) -> no L2-reuse dependence.
// Adds (norm - score)/B into out[0].
__global__ __launch_bounds__(1024) void crf_row_kernel(
    const float* __restrict__ em,     // (B,S,2)
    const float* __restrict__ st,     // (2,)
    const float* __restrict__ en,     // (2,)
    const float* __restrict__ tr,     // (2,2)
    const int*   __restrict__ tags,   // (B,S)
    const int*   __restrict__ lens,   // (B,)
    float* __restrict__ out)          // scalar accumulator (pre-zeroed)
{
    const int b   = blockIdx.x;
    const int tid = threadIdx.x;
    const int lane = tid & 63, wid = tid >> 6;
    const float* em_row = em   + (size_t)b * S_CONST * 2;
    const int*   tg_row = tags + (size_t)b * S_CONST;

    const int L = lens[b];            // broadcast load

    const float t00 = tr[0], t01 = tr[1], t10 = tr[2], t11 = tr[3];

    const int c0   = tid * 4;         // 4 steps per thread
    const int myHi = min(c0 + 4, L);
    const bool active = (c0 < L);

    // log-semiring identity
    Seg seg; seg.m00 = 0.0f; seg.m11 = 0.0f; seg.m01 = NEGBIG; seg.m10 = NEGBIG;
    float sc = 0.0f;

    int4 tg4 = make_int4(0, 0, 0, 0);
    if (active) tg4 = *(const int4*)(tg_row + c0);          // coalesced 16 B/lane

    // prev tag = tg_row[c0-1]: last element of the previous lane's int4.
    int prev = __shfl_up(tg4.w, 1);
    if (lane == 0) prev = (c0 > 0 && active) ? tg_row[c0 - 1] : 0;

    if (active) {
        const float4* emv = (const float4*)(em_row + 2 * c0);
        float4 eA = emv[0];           // t = c0, c0+1
        float4 eB = emv[1];           // t = c0+2, c0+3

        #define STEP(T_, E0_, E1_, TG_)                                      \
            do {                                                             \
                int t_ = (T_);                                               \
                if (t_ >= 1 && t_ < myHi) {                                  \
                    float e0_ = (E0_), e1_ = (E1_);                          \
                    Seg M;                                                   \
                    M.m00 = t00 + e0_; M.m01 = t01 + e1_;                    \
                    M.m10 = t10 + e0_; M.m11 = t11 + e1_;                    \
                    seg = seg_compose(seg, M);                               \
                    float trv = prev ? ((TG_) ? t11 : t10)                   \
                                     : ((TG_) ? t01 : t00);                  \
                    sc += trv + ((TG_) ? e1_ : e0_);                         \
                }                                                            \
                prev = (TG_);                                                \
            } while (0)

        STEP(c0 + 0, eA.x, eA.y, tg4.x);
        STEP(c0 + 1, eA.z, eA.w, tg4.y);
        STEP(c0 + 2, eB.x, eB.y, tg4.z);
        STEP(c0 + 3, eB.z, eB.w, tg4.w);
        #undef STEP
    }

    // Ordered wave-level tree reduce (lane i covers contiguous chunk i; left ⊗ right).
    #pragma unroll
    for (int s = 1; s < 64; s <<= 1) {
        Seg r;
        r.m00 = __shfl_down(seg.m00, s);
        r.m01 = __shfl_down(seg.m01, s);
        r.m10 = __shfl_down(seg.m10, s);
        r.m11 = __shfl_down(seg.m11, s);
        float rsc = __shfl_down(sc, s);
        seg = seg_compose(seg, r);
        sc += rsc;
    }

    __shared__ Seg   wseg[16];
    __shared__ float wsc[16];
    if (lane == 0) { wseg[wid] = seg; wsc[wid] = sc; }
    __syncthreads();

    if (tid == 0) {
        Seg P = wseg[0];
        float scT = wsc[0];
        #pragma unroll
        for (int w = 1; w < 16; ++w) { P = seg_compose(P, wseg[w]); scT += wsc[w]; }

        float e00 = em_row[0], e01 = em_row[1];
        float st0 = st[0], st1 = st[1];
        float en0 = en[0], en1 = en[1];

        // normalizer: init = start + em[0]; apply segment matrix P (steps 1..L-1)
        float i0 = st0 + e00, i1 = st1 + e01;
        float f0 = lse2(i0 + P.m00, i1 + P.m10);
        float f1 = lse2(i0 + P.m01, i1 + P.m11);
        float norm = lse2(f0 + en0, f1 + en1);

        int tg0 = tg_row[0];
        int tgL = tg_row[L - 1];
        float score = (tg0 ? st1 : st0) + (tg0 ? e01 : e00) + scT
                    + (tgL ? en1 : en0);

        atomicAdd(out, (norm - score) * (1.0f / (float)B_CONST));
    }
}

extern "C" void kernel_launch(void* const* d_in, const int* in_sizes, int n_in,
                              void* d_out, int out_size, void* d_ws, size_t ws_size,
                              hipStream_t stream) {
    const float* em   = (const float*)d_in[0];
    const float* st   = (const float*)d_in[1];
    const float* en   = (const float*)d_in[2];
    const float* tr   = (const float*)d_in[3];
    const int*   tags = (const int*)d_in[4];
    const int*   mask = (const int*)d_in[5];

    int*   lens = (int*)d_ws;       // B ints
    float* out  = (float*)d_out;

    hipMemsetAsync(out, 0, sizeof(float) * out_size, stream);
    crf_lens_kernel<<<(B_CONST + 3) / 4, 256, 0, stream>>>(mask, lens);
    crf_row_kernel<<<B_CONST, 1024, 0, stream>>>(em, st, en, tr, tags, lens, out);
}

// Round 3
// 290.556 us; speedup vs baseline: 1.1162x; 1.1162x over previous
//
#include <hip/hip_runtime.h>

#define B_CONST 4096
#define S_CONST 4096
// T == 2 hardcoded throughout.

#define NEGBIG (-1e30f)

__device__ __forceinline__ float lse2(float a, float b) {
    float m = fmaxf(a, b);
    float d = fminf(a, b) - m;          // <= 0, finite (sentinels are -1e30, not -inf)
    return m + __logf(1.0f + __expf(d));
}

struct Seg { float m00, m01, m10, m11; };

__device__ __forceinline__ Seg seg_compose(const Seg& L, const Seg& R) {
    Seg o;
    o.m00 = lse2(L.m00 + R.m00, L.m01 + R.m10);
    o.m01 = lse2(L.m00 + R.m01, L.m01 + R.m11);
    o.m10 = lse2(L.m10 + R.m00, L.m11 + R.m10);
    o.m11 = lse2(L.m10 + R.m01, L.m11 + R.m11);
    return o;
}

// XOR swizzle: logical slot s -> physical LDS slot. Breaks the stride-16
// read pattern (lane i reads slots 16i+k) into 8 bank-groups instead of 1.
__device__ __forceinline__ int swz(int s) { return s ^ ((s >> 4) & 15); }

// One 1024-thread block per batch row; 4 steps/thread (coalesced 16B/lane
// loads, proven ideal-FETCH in R2). Final reduce: LDS stash + wave-0
// lane-serial compose (replaces the 24.6k-lse2 full-width shuffle tree).
__global__ __launch_bounds__(1024) void crf_row_kernel(
    const float* __restrict__ em,     // (B,S,2)
    const float* __restrict__ st,     // (2,)
    const float* __restrict__ en,     // (2,)
    const float* __restrict__ tr,     // (2,2)
    const int*   __restrict__ tags,   // (B,S)
    const int*   __restrict__ mask,   // (B,S) prefix-of-ones rows
    float* __restrict__ out)          // scalar accumulator (pre-zeroed)
{
    const int b    = blockIdx.x;
    const int tid  = threadIdx.x;
    const int lane = tid & 63;

    const float* em_row = em   + (size_t)b * S_CONST * 2;
    const int*   tg_row = tags + (size_t)b * S_CONST;
    const int*   mk     = mask + (size_t)b * S_CONST;

    // Per-wave 2-phase ballot search for L = count of leading 1s (L >= S/2).
    // All 16 waves redundantly do this (2 loads each, L1-deduped) -> no
    // extra barrier and no separate kernel.
    int v1 = mk[lane << 6];
    unsigned long long bal1 = __ballot(v1 != 0);
    int base = (__popcll(bal1) - 1) << 6;
    int v2 = mk[base + lane];
    const int L = base + __popcll(__ballot(v2 != 0));

    const float t00 = tr[0], t01 = tr[1], t10 = tr[2], t11 = tr[3];

    const int  c0     = tid * 4;          // 4 steps per thread
    const int  myHi   = min(c0 + 4, L);
    const bool active = (c0 < L);
    const int  lo     = (c0 == 0) ? 1 : c0;   // first step index this thread owns

    // log-semiring identity (threads with no valid steps contribute this)
    Seg seg; seg.m00 = 0.0f; seg.m11 = 0.0f; seg.m01 = NEGBIG; seg.m10 = NEGBIG;
    float sc = 0.0f;

    int4 tg4 = make_int4(0, 0, 0, 0);
    if (active) tg4 = *(const int4*)(tg_row + c0);          // coalesced 16 B/lane

    // prev tag = tg_row[c0-1]: last element of the previous lane's int4.
    int prev = __shfl_up(tg4.w, 1);
    if (lane == 0) prev = (c0 > 0 && active) ? tg_row[c0 - 1] : 0;

    if (active) {
        const float4* emv = (const float4*)(em_row + 2 * c0);
        float4 eA = emv[0];           // t = c0, c0+1
        float4 eB = emv[1];           // t = c0+2, c0+3

        // First valid step initializes seg directly (no identity compose).
        #define STEP(T_, E0_, E1_, TG_)                                      \
            do {                                                             \
                int t_ = (T_);                                               \
                if (t_ >= 1 && t_ < myHi) {                                  \
                    float e0_ = (E0_), e1_ = (E1_);                          \
                    Seg M;                                                   \
                    M.m00 = t00 + e0_; M.m01 = t01 + e1_;                    \
                    M.m10 = t10 + e0_; M.m11 = t11 + e1_;                    \
                    if (t_ == lo) seg = M;                                   \
                    else          seg = seg_compose(seg, M);                 \
                    float trv = prev ? ((TG_) ? t11 : t10)                   \
                                     : ((TG_) ? t01 : t00);                  \
                    sc += trv + ((TG_) ? e1_ : e0_);                         \
                }                                                            \
                prev = (TG_);                                                \
            } while (0)

        STEP(c0 + 0, eA.x, eA.y, tg4.x);
        STEP(c0 + 1, eA.z, eA.w, tg4.y);
        STEP(c0 + 2, eB.x, eB.y, tg4.z);
        STEP(c0 + 3, eB.z, eB.w, tg4.w);
        #undef STEP
    }

    // Stash all 1024 thread-segments in LDS (swizzled), then wave 0 alone
    // reduces: lane i composes slots 16i..16i+15 serially (order preserved),
    // then a 6-level shuffle tree over 64 lanes.
    __shared__ float4 ssegs[1024];      // 16 KB
    __shared__ float  sscs[1024];       //  4 KB
    const int ph = swz(tid);
    ssegs[ph] = make_float4(seg.m00, seg.m01, seg.m10, seg.m11);
    sscs[ph]  = sc;
    __syncthreads();

    if (tid < 64) {
        const int s0 = tid << 4;
        float4 v = ssegs[swz(s0)];
        Seg P; P.m00 = v.x; P.m01 = v.y; P.m10 = v.z; P.m11 = v.w;
        float scT = sscs[swz(s0)];
        #pragma unroll
        for (int k = 1; k < 16; ++k) {
            const int p = swz(s0 + k);
            float4 r4 = ssegs[p];
            Seg R; R.m00 = r4.x; R.m01 = r4.y; R.m10 = r4.z; R.m11 = r4.w;
            P = seg_compose(P, R);
            scT += sscs[p];
        }

        #pragma unroll
        for (int s = 1; s < 64; s <<= 1) {
            Seg r;
            r.m00 = __shfl_down(P.m00, s);
            r.m01 = __shfl_down(P.m01, s);
            r.m10 = __shfl_down(P.m10, s);
            r.m11 = __shfl_down(P.m11, s);
            float rsc = __shfl_down(scT, s);
            P = seg_compose(P, r);
            scT += rsc;
        }

        if (tid == 0) {
            float e00 = em_row[0], e01 = em_row[1];
            float st0 = st[0], st1 = st[1];
            float en0 = en[0], en1 = en[1];

            // normalizer: init = start + em[0]; apply segment product P (steps 1..L-1)
            float i0 = st0 + e00, i1 = st1 + e01;
            float f0 = lse2(i0 + P.m00, i1 + P.m10);
            float f1 = lse2(i0 + P.m01, i1 + P.m11);
            float norm = lse2(f0 + en0, f1 + en1);

            int tg0 = tg_row[0];
            int tgL = tg_row[L - 1];
            float score = (tg0 ? st1 : st0) + (tg0 ? e01 : e00) + scT
                        + (tgL ? en1 : en0);

            atomicAdd(out, (norm - score) * (1.0f / (float)B_CONST));
        }
    }
}

extern "C" void kernel_launch(void* const* d_in, const int* in_sizes, int n_in,
                              void* d_out, int out_size, void* d_ws, size_t ws_size,
                              hipStream_t stream) {
    const float* em   = (const float*)d_in[0];
    const float* st   = (const float*)d_in[1];
    const float* en   = (const float*)d_in[2];
    const float* tr   = (const float*)d_in[3];
    const int*   tags = (const int*)d_in[4];
    const int*   mask = (const int*)d_in[5];

    float* out = (float*)d_out;

    hipMemsetAsync(out, 0, sizeof(float) * out_size, stream);
    crf_row_kernel<<<B_CONST, 1024, 0, stream>>>(em, st, en, tr, tags, mask, out);
}

// Round 4
// 289.495 us; speedup vs baseline: 1.1203x; 1.0037x over previous
//
#include <hip/hip_runtime.h>

#define B_CONST 4096
#define S_CONST 4096
// T == 2 hardcoded throughout.

#define NEGBIG (-1e30f)
#define LOG2E  1.44269504088896340736f
#define LN2    0.69314718055994530942f

// log-sum-exp in the BASE-2 domain: inputs/outputs are scores * log2(e).
// v_exp_f32 / v_log_f32 are natively base-2 -> no hidden multiplies.
__device__ __forceinline__ float lse2b(float a, float b) {
    float m = fmaxf(a, b);
    float d = fminf(a, b) - m;          // <= 0, finite (sentinels are -1e30)
    return m + __log2f(1.0f + exp2f(d));
}

struct Seg { float m00, m01, m10, m11; };

__device__ __forceinline__ Seg seg_compose(const Seg& L, const Seg& R) {
    Seg o;
    o.m00 = lse2b(L.m00 + R.m00, L.m01 + R.m10);
    o.m01 = lse2b(L.m00 + R.m01, L.m01 + R.m11);
    o.m10 = lse2b(L.m10 + R.m00, L.m11 + R.m10);
    o.m11 = lse2b(L.m10 + R.m01, L.m11 + R.m11);
    return o;
}

// Kernel 0: one wave per row; 2-phase ballot search for L = count of leading
// 1s (mask rows are prefix-of-ones, L >= S/2 >= 2048).
__global__ __launch_bounds__(256) void crf_lens_kernel(
    const int* __restrict__ mask, int* __restrict__ lens)
{
    const int lane = threadIdx.x & 63;
    const int wid  = threadIdx.x >> 6;
    const int b    = blockIdx.x * 4 + wid;
    if (b >= B_CONST) return;
    const int* mk = mask + (size_t)b * S_CONST;
    int v1 = mk[lane << 6];
    unsigned long long bal1 = __ballot(v1 != 0);
    int base = (__popcll(bal1) - 1) << 6;
    int v2 = mk[base + lane];
    if (lane == 0) lens[b] = base + __popcll(__ballot(v2 != 0));
}

// Kernel A: 4 independent waves per row (chunk = 1024 steps, 16 steps/lane).
// No LDS, no barrier. Each wave emits one Seg (base-2 domain) + raw score
// partial. 12 x 16B loads per lane keeps plenty of MLP in flight.
__global__ __launch_bounds__(256) void crf_scan_kernel(
    const float* __restrict__ em,     // (B,S,2)
    const float* __restrict__ tr,     // (2,2)
    const int*   __restrict__ tags,   // (B,S)
    const int*   __restrict__ lens,   // (B,)
    float4*      __restrict__ wsegs,  // (B,4)
    float*       __restrict__ wscs)   // (B,4)
{
    const int b    = blockIdx.x;
    const int wid  = threadIdx.x >> 6;     // chunk index 0..3
    const int lane = threadIdx.x & 63;
    const int cb   = wid << 10;            // chunk base step
    const int c0   = cb + (lane << 4);     // this lane's first step

    const float* em_row = em   + (size_t)b * S_CONST * 2;
    const int*   tg_row = tags + (size_t)b * S_CONST;
    const int    L      = lens[b];

    const float t00 = tr[0], t01 = tr[1], t10 = tr[2], t11 = tr[3];
    const float s00 = t00 * LOG2E, s01 = t01 * LOG2E;
    const float s10 = t10 * LOG2E, s11 = t11 * LOG2E;

    const int  myHi   = min(c0 + 16, L);
    const bool active = (c0 < L);
    const int  lo     = (c0 == 0) ? 1 : c0;   // first valid step this lane owns

    Seg seg; seg.m00 = 0.0f; seg.m11 = 0.0f; seg.m01 = NEGBIG; seg.m10 = NEGBIG;
    float sc = 0.0f;

    int4 tgq[4] = {{0,0,0,0},{0,0,0,0},{0,0,0,0},{0,0,0,0}};
    if (active) {
        const int4* tv = (const int4*)(tg_row + c0);
        tgq[0] = tv[0]; tgq[1] = tv[1]; tgq[2] = tv[2]; tgq[3] = tv[3];
    }
    // prev tag = tg_row[c0-1]: last tag of the previous lane's chunk.
    int prev = __shfl_up(tgq[3].w, 1);
    if (lane == 0) prev = (cb > 0) ? tg_row[cb - 1] : 0;

    if (active) {
        const float4* ev = (const float4*)(em_row + 2 * c0);

        #define STEP(T_, E0_, E1_, TG_)                                      \
            do {                                                             \
                int t_ = (T_);                                               \
                if (t_ >= 1 && t_ < myHi) {                                  \
                    float e0_ = (E0_), e1_ = (E1_);                          \
                    float e0s = e0_ * LOG2E, e1s = e1_ * LOG2E;              \
                    Seg M;                                                   \
                    M.m00 = s00 + e0s; M.m01 = s01 + e1s;                    \
                    M.m10 = s10 + e0s; M.m11 = s11 + e1s;                    \
                    if (t_ == lo) seg = M;                                   \
                    else          seg = seg_compose(seg, M);                 \
                    float trv = prev ? ((TG_) ? t11 : t10)                   \
                                     : ((TG_) ? t01 : t00);                  \
                    sc += trv + ((TG_) ? e1_ : e0_);                         \
                }                                                            \
                prev = (TG_);                                                \
            } while (0)

        #pragma unroll
        for (int g = 0; g < 4; ++g) {
            const int tb = c0 + 4 * g;
            if (tb < myHi) {
                float4 eA = ev[2 * g];
                float4 eB = ev[2 * g + 1];
                int4   t4 = tgq[g];
                STEP(tb + 0, eA.x, eA.y, t4.x);
                STEP(tb + 1, eA.z, eA.w, t4.y);
                STEP(tb + 2, eB.x, eB.y, t4.z);
                STEP(tb + 3, eB.z, eB.w, t4.w);
            }
        }
        #undef STEP
    }

    // Ordered in-wave tree (lane i holds contiguous chunk i; left-compose-right).
    #pragma unroll
    for (int s = 1; s < 64; s <<= 1) {
        Seg r;
        r.m00 = __shfl_down(seg.m00, s);
        r.m01 = __shfl_down(seg.m01, s);
        r.m10 = __shfl_down(seg.m10, s);
        r.m11 = __shfl_down(seg.m11, s);
        float rsc = __shfl_down(sc, s);
        seg = seg_compose(seg, r);
        sc += rsc;
    }

    if (lane == 0) {
        wsegs[b * 4 + wid] = make_float4(seg.m00, seg.m01, seg.m10, seg.m11);
        wscs [b * 4 + wid] = sc;
    }
}

// Kernel B: one lane per row. Compose the row's 4 wave-segs (ordered), apply
// init/end vectors, finish score, reduce mean via atomicAdd.
__global__ __launch_bounds__(256) void crf_final_kernel(
    const float* __restrict__ em,
    const float* __restrict__ st,
    const float* __restrict__ en,
    const int*   __restrict__ tags,
    const int*   __restrict__ lens,
    const float4* __restrict__ wsegs,
    const float* __restrict__ wscs,
    float* __restrict__ out)
{
    const int r = blockIdx.x * 256 + threadIdx.x;   // r < B_CONST always

    float4 v = wsegs[r * 4];
    Seg P; P.m00 = v.x; P.m01 = v.y; P.m10 = v.z; P.m11 = v.w;
    float scT = wscs[r * 4];
    #pragma unroll
    for (int w = 1; w < 4; ++w) {
        float4 rv = wsegs[r * 4 + w];
        Seg R; R.m00 = rv.x; R.m01 = rv.y; R.m10 = rv.z; R.m11 = rv.w;
        P = seg_compose(P, R);
        scT += wscs[r * 4 + w];
    }

    const float* em_row = em   + (size_t)r * S_CONST * 2;
    const int*   tg_row = tags + (size_t)r * S_CONST;
    const int    L      = lens[r];

    float e00 = em_row[0], e01 = em_row[1];
    float st0 = st[0], st1 = st[1];
    float en0 = en[0], en1 = en[1];

    float i0 = (st0 + e00) * LOG2E, i1 = (st1 + e01) * LOG2E;
    float f0 = lse2b(i0 + P.m00, i1 + P.m10);
    float f1 = lse2b(i0 + P.m01, i1 + P.m11);
    float norm = lse2b(f0 + en0 * LOG2E, f1 + en1 * LOG2E) * LN2;

    int tg0 = tg_row[0];
    int tgL = tg_row[L - 1];
    float score = (tg0 ? st1 : st0) + (tg0 ? e01 : e00) + scT
                + (tgL ? en1 : en0);

    float nll = norm - score;

    #pragma unroll
    for (int d = 32; d >= 1; d >>= 1) nll += __shfl_down(nll, d);
    if ((threadIdx.x & 63) == 0) atomicAdd(out, nll * (1.0f / (float)B_CONST));
}

extern "C" void kernel_launch(void* const* d_in, const int* in_sizes, int n_in,
                              void* d_out, int out_size, void* d_ws, size_t ws_size,
                              hipStream_t stream) {
    const float* em   = (const float*)d_in[0];
    const float* st   = (const float*)d_in[1];
    const float* en   = (const float*)d_in[2];
    const float* tr   = (const float*)d_in[3];
    const int*   tags = (const int*)d_in[4];
    const int*   mask = (const int*)d_in[5];

    // ws layout: wsegs (B*4 float4 = 256 KB) | wscs (B*4 float = 64 KB) | lens (B int = 16 KB)
    float4* wsegs = (float4*)d_ws;
    float*  wscs  = (float*)((char*)d_ws + (size_t)B_CONST * 4 * sizeof(float4));
    int*    lens  = (int*)((char*)wscs + (size_t)B_CONST * 4 * sizeof(float));

    float* out = (float*)d_out;

    hipMemsetAsync(out, 0, sizeof(float) * out_size, stream);
    crf_lens_kernel<<<(B_CONST + 3) / 4, 256, 0, stream>>>(mask, lens);
    crf_scan_kernel<<<B_CONST, 256, 0, stream>>>(em, tr, tags, lens, wsegs, wscs);
    crf_final_kernel<<<B_CONST / 256, 256, 0, stream>>>(em, st, en, tags, lens, wsegs, wscs, out);
}

// Round 5
// 286.110 us; speedup vs baseline: 1.1336x; 1.0118x over previous
//
#include <hip/hip_runtime.h>

#define B_CONST 4096
#define S_CONST 4096
// T == 2 hardcoded throughout.

#define NEGBIG (-1e30f)

__device__ __forceinline__ float lse2(float a, float b) {
    float m = fmaxf(a, b);
    float d = fminf(a, b) - m;          // <= 0, finite (sentinels are -1e30, not -inf)
    return m + __logf(1.0f + __expf(d));
}

struct Seg { float m00, m01, m10, m11; };

__device__ __forceinline__ Seg seg_compose(const Seg& L, const Seg& R) {
    Seg o;
    o.m00 = lse2(L.m00 + R.m00, L.m01 + R.m10);
    o.m01 = lse2(L.m00 + R.m01, L.m01 + R.m11);
    o.m10 = lse2(L.m10 + R.m00, L.m11 + R.m10);
    o.m11 = lse2(L.m10 + R.m01, L.m11 + R.m11);
    return o;
}

// One 256-thread block (4 waves) per row. Wave w owns steps [1024w, 1024w+1024),
// 16 steps/lane. All 12x16B loads per lane are UNCONDITIONAL within a
// participating wave (addresses always in-bounds; only values are masked) so
// the full load set is in flight before the compose chain starts.
// No workspace, one barrier, 80 B LDS.
__global__ __launch_bounds__(256) void crf_row_kernel(
    const float* __restrict__ em,     // (B,S,2)
    const float* __restrict__ st,     // (2,)
    const float* __restrict__ en,     // (2,)
    const float* __restrict__ tr,     // (2,2)
    const int*   __restrict__ tags,   // (B,S)
    const int*   __restrict__ mask,   // (B,S) prefix-of-ones rows
    float* __restrict__ out)          // scalar accumulator (pre-zeroed)
{
    const int b    = blockIdx.x;
    const int tid  = threadIdx.x;
    const int lane = tid & 63;
    const int wid  = tid >> 6;        // wave chunk 0..3
    const int cb   = wid << 10;       // chunk base step
    const int c0   = cb + (lane << 4);// this lane's first step

    const float* em_row = em   + (size_t)b * S_CONST * 2;
    const int*   tg_row = tags + (size_t)b * S_CONST;
    const int*   mk     = mask + (size_t)b * S_CONST;

    // Per-wave 2-phase ballot search for L = count of leading 1s (L >= 2048).
    int v1 = mk[lane << 6];
    unsigned long long bal1 = __ballot(v1 != 0);
    int base = (__popcll(bal1) - 1) << 6;
    int v2 = mk[base + lane];
    const int L = base + __popcll(__ballot(v2 != 0));

    const float t00 = tr[0], t01 = tr[1], t10 = tr[2], t11 = tr[3];

    // log-semiring identity
    Seg seg; seg.m00 = 0.0f; seg.m11 = 0.0f; seg.m01 = NEGBIG; seg.m10 = NEGBIG;
    float sc = 0.0f;

    __shared__ float4 wseg[4];
    __shared__ float  wsc[4];

    if (cb < L) {                      // wave-uniform: this wave has work
        // ---- all loads issued up front, unguarded (in-bounds by construction)
        const int4* tv = (const int4*)(tg_row + c0);
        int4 tq0 = tv[0], tq1 = tv[1], tq2 = tv[2], tq3 = tv[3];
        const float4* ev = (const float4*)(em_row + 2 * c0);
        float4 e0 = ev[0], e1 = ev[1], e2 = ev[2], e3 = ev[3];
        float4 e4 = ev[4], e5 = ev[5], e6 = ev[6], e7 = ev[7];

        // prev tag = tg_row[c0-1]: last tag of the previous lane's chunk.
        int prev = __shfl_up(tq3.w, 1);
        if (lane == 0) prev = (cb > 0) ? tg_row[cb - 1] : 0;

        const int myHi = min(c0 + 16, L);
        const int lo   = (c0 == 0) ? 1 : c0;   // first step this lane owns

        #define STEP(T_, E0_, E1_, TG_)                                      \
            do {                                                             \
                int t_ = (T_);                                               \
                if (t_ >= 1 && t_ < myHi) {                                  \
                    float e0_ = (E0_), e1_ = (E1_);                          \
                    Seg M;                                                   \
                    M.m00 = t00 + e0_; M.m01 = t01 + e1_;                    \
                    M.m10 = t10 + e0_; M.m11 = t11 + e1_;                    \
                    if (t_ == lo) seg = M;                                   \
                    else          seg = seg_compose(seg, M);                 \
                    float trv = prev ? ((TG_) ? t11 : t10)                   \
                                     : ((TG_) ? t01 : t00);                  \
                    sc += trv + ((TG_) ? e1_ : e0_);                         \
                }                                                            \
                prev = (TG_);                                                \
            } while (0)

        STEP(c0 +  0, e0.x, e0.y, tq0.x);
        STEP(c0 +  1, e0.z, e0.w, tq0.y);
        STEP(c0 +  2, e1.x, e1.y, tq0.z);
        STEP(c0 +  3, e1.z, e1.w, tq0.w);
        STEP(c0 +  4, e2.x, e2.y, tq1.x);
        STEP(c0 +  5, e2.z, e2.w, tq1.y);
        STEP(c0 +  6, e3.x, e3.y, tq1.z);
        STEP(c0 +  7, e3.z, e3.w, tq1.w);
        STEP(c0 +  8, e4.x, e4.y, tq2.x);
        STEP(c0 +  9, e4.z, e4.w, tq2.y);
        STEP(c0 + 10, e5.x, e5.y, tq2.z);
        STEP(c0 + 11, e5.z, e5.w, tq2.w);
        STEP(c0 + 12, e6.x, e6.y, tq3.x);
        STEP(c0 + 13, e6.z, e6.w, tq3.y);
        STEP(c0 + 14, e7.x, e7.y, tq3.z);
        STEP(c0 + 15, e7.z, e7.w, tq3.w);
        #undef STEP

        // Ordered in-wave tree (lane i holds contiguous chunk i).
        #pragma unroll
        for (int s = 1; s < 64; s <<= 1) {
            Seg r;
            r.m00 = __shfl_down(seg.m00, s);
            r.m01 = __shfl_down(seg.m01, s);
            r.m10 = __shfl_down(seg.m10, s);
            r.m11 = __shfl_down(seg.m11, s);
            float rsc = __shfl_down(sc, s);
            seg = seg_compose(seg, r);
            sc += rsc;
        }
    }

    if (lane == 0) {                   // inactive waves publish identity
        wseg[wid] = make_float4(seg.m00, seg.m01, seg.m10, seg.m11);
        wsc[wid]  = sc;
    }
    __syncthreads();

    if (tid == 0) {
        float4 v = wseg[0];
        Seg P; P.m00 = v.x; P.m01 = v.y; P.m10 = v.z; P.m11 = v.w;
        float scT = wsc[0];
        #pragma unroll
        for (int w = 1; w < 4; ++w) {
            float4 rv = wseg[w];
            Seg R; R.m00 = rv.x; R.m01 = rv.y; R.m10 = rv.z; R.m11 = rv.w;
            P = seg_compose(P, R);
            scT += wsc[w];
        }

        float e00 = em_row[0], e01 = em_row[1];
        float st0 = st[0], st1 = st[1];
        float en0 = en[0], en1 = en[1];

        // normalizer: init = start + em[0]; apply product P of steps 1..L-1
        float i0 = st0 + e00, i1 = st1 + e01;
        float f0 = lse2(i0 + P.m00, i1 + P.m10);
        float f1 = lse2(i0 + P.m01, i1 + P.m11);
        float norm = lse2(f0 + en0, f1 + en1);

        int tg0 = tg_row[0];
        int tgL = tg_row[L - 1];
        float score = (tg0 ? st1 : st0) + (tg0 ? e01 : e00) + scT
                    + (tgL ? en1 : en0);

        atomicAdd(out, (norm - score) * (1.0f / (float)B_CONST));
    }
}

extern "C" void kernel_launch(void* const* d_in, const int* in_sizes, int n_in,
                              void* d_out, int out_size, void* d_ws, size_t ws_size,
                              hipStream_t stream) {
    const float* em   = (const float*)d_in[0];
    const float* st   = (const float*)d_in[1];
    const float* en   = (const float*)d_in[2];
    const float* tr   = (const float*)d_in[3];
    const int*   tags = (const int*)d_in[4];
    const int*   mask = (const int*)d_in[5];

    float* out = (float*)d_out;

    hipMemsetAsync(out, 0, sizeof(float) * out_size, stream);
    crf_row_kernel<<<B_CONST, 256, 0, stream>>>(em, st, en, tr, tags, mask, out);
}